// Round 1
// baseline (634.298 us; speedup 1.0000x reference)
//
#include <hip/hip_runtime.h>
#include <hip/hip_bf16.h>
#include <cstdint>
#include <cstddef>

#define N_NODES 50000
#define N_EDGES 800000
#define D_FEAT  128
#define HALF    64
#define HIDDEN  256
#define LABELS  40

// ---------------------------------------------------------------------------
// CSR build: degree histogram -> exclusive scan -> bucket fill
// ---------------------------------------------------------------------------
__global__ void deg_kernel(const int* __restrict__ row, int* __restrict__ deg) {
    int e = blockIdx.x * blockDim.x + threadIdx.x;
    if (e < N_EDGES) atomicAdd(&deg[row[e]], 1);
}

// Single-block Hillis-Steele scan over N_NODES (49 chunks of 1024).
__global__ void scan_kernel(const int* __restrict__ deg, int* __restrict__ rowstart,
                            float* __restrict__ inv_deg) {
    __shared__ int buf[1024];
    __shared__ int carry_s;
    int tid = threadIdx.x;
    if (tid == 0) carry_s = 0;
    __syncthreads();
    for (int base = 0; base < N_NODES; base += 1024) {
        int i = base + tid;
        int v = (i < N_NODES) ? deg[i] : 0;
        int acc = v;
        buf[tid] = v;
        __syncthreads();
        for (int off = 1; off < 1024; off <<= 1) {
            int t = (tid >= off) ? buf[tid - off] : 0;
            __syncthreads();
            acc += t;
            buf[tid] = acc;
            __syncthreads();
        }
        if (i < N_NODES) {
            rowstart[i] = carry_s + acc - v;      // exclusive
            inv_deg[i]  = 1.0f / fmaxf((float)v, 1.0f);
        }
        __syncthreads();                          // all carry_s reads done
        if (tid == 1023) carry_s += acc;          // acc(1023) == chunk total
        __syncthreads();                          // carry visible next chunk
    }
}

__global__ void fill_kernel(const int* __restrict__ row, const int* __restrict__ col,
                            const int* __restrict__ rowstart, int* __restrict__ cursor,
                            int* __restrict__ csr_col) {
    int e = blockIdx.x * blockDim.x + threadIdx.x;
    if (e < N_EDGES) {
        int r = row[e];
        int pos = atomicAdd(&cursor[r], 1);
        csr_col[rowstart[r] + pos] = col[e];
    }
}

// ---------------------------------------------------------------------------
// Mean-neighbor aggregation: one wave (64 lanes) per node, float2 per lane.
// Each edge read is one coalesced 512 B row. Writes nbr_mean (pre-scaled).
// ---------------------------------------------------------------------------
__global__ __launch_bounds__(256) void agg_kernel(
        const float* __restrict__ h, const int* __restrict__ csr_col,
        const int* __restrict__ rowstart, const int* __restrict__ deg,
        const float* __restrict__ inv_deg, float* __restrict__ nbr) {
    int gid  = blockIdx.x * blockDim.x + threadIdx.x;
    int node = gid >> 6;
    int lane = threadIdx.x & 63;
    if (node >= N_NODES) return;
    int start = rowstart[node];
    int d     = deg[node];
    float a0 = 0.f, a1 = 0.f;
    int j = 0;
    for (; j + 4 <= d; j += 4) {
        int s0 = csr_col[start + j + 0];
        int s1 = csr_col[start + j + 1];
        int s2 = csr_col[start + j + 2];
        int s3 = csr_col[start + j + 3];
        float2 v0 = *(const float2*)(h + (size_t)s0 * D_FEAT + lane * 2);
        float2 v1 = *(const float2*)(h + (size_t)s1 * D_FEAT + lane * 2);
        float2 v2 = *(const float2*)(h + (size_t)s2 * D_FEAT + lane * 2);
        float2 v3 = *(const float2*)(h + (size_t)s3 * D_FEAT + lane * 2);
        a0 += v0.x + v1.x + v2.x + v3.x;
        a1 += v0.y + v1.y + v2.y + v3.y;
    }
    for (; j < d; ++j) {
        int s = csr_col[start + j];
        float2 v = *(const float2*)(h + (size_t)s * D_FEAT + lane * 2);
        a0 += v.x; a1 += v.y;
    }
    float inv = inv_deg[node];
    float2 o; o.x = a0 * inv; o.y = a1 * inv;
    *(float2*)(nbr + (size_t)node * D_FEAT + lane * 2) = o;
}

// ---------------------------------------------------------------------------
// Layer GEMM: h_out[N,128] = relu([h@Wself | nbr@Wnbr] + bias)
// 32-row tiles in LDS (stride 132 to decouple banks), 4x4 register blocking.
// ---------------------------------------------------------------------------
__global__ __launch_bounds__(256) void layer_kernel(
        const float* __restrict__ h, const float* __restrict__ nbr,
        const float* __restrict__ wself, const float* __restrict__ wnbr,
        const float* __restrict__ bias, float* __restrict__ out) {
    __shared__ float hs[32][132];
    __shared__ float ns[32][132];
    int tid  = threadIdx.x;
    int row0 = blockIdx.x * 32;
    for (int t = tid; t < 1024; t += 256) {
        int r = t >> 5;
        int c = (t & 31) * 4;
        int gr = row0 + r;
        float4 hv = make_float4(0.f, 0.f, 0.f, 0.f);
        float4 nv = make_float4(0.f, 0.f, 0.f, 0.f);
        if (gr < N_NODES) {
            hv = *(const float4*)(h   + (size_t)gr * D_FEAT + c);
            nv = *(const float4*)(nbr + (size_t)gr * D_FEAT + c);
        }
        *(float4*)&hs[r][c] = hv;
        *(float4*)&ns[r][c] = nv;
    }
    __syncthreads();

    int tr = tid >> 5;        // 0..7 -> 4 rows each
    int tc = tid & 31;        // 0..31 -> 4 cols each
    int j0 = tc * 4;          // 0..124
    bool self_half = (j0 < HALF);
    const float (*A)[132] = self_half ? hs : ns;
    const float* W = self_half ? (wself + j0) : (wnbr + (j0 - HALF));
    int ra = tr * 4;

    float acc[4][4];
    float b0 = bias[j0], b1 = bias[j0 + 1], b2 = bias[j0 + 2], b3 = bias[j0 + 3];
#pragma unroll
    for (int r = 0; r < 4; r++) { acc[r][0] = b0; acc[r][1] = b1; acc[r][2] = b2; acc[r][3] = b3; }

    for (int k = 0; k < D_FEAT; k += 4) {
        float4 a[4];
#pragma unroll
        for (int r = 0; r < 4; r++) a[r] = *(const float4*)&A[ra + r][k];
#pragma unroll
        for (int kk = 0; kk < 4; kk++) {
            float4 b = *(const float4*)(W + (size_t)(k + kk) * HALF);
#pragma unroll
            for (int r = 0; r < 4; r++) {
                float av = (&a[r].x)[kk];
                acc[r][0] += av * b.x;
                acc[r][1] += av * b.y;
                acc[r][2] += av * b.z;
                acc[r][3] += av * b.w;
            }
        }
    }
#pragma unroll
    for (int r = 0; r < 4; r++) {
        int gr = row0 + ra + r;
        if (gr < N_NODES) {
            float4 o;
            o.x = fmaxf(acc[r][0], 0.f);
            o.y = fmaxf(acc[r][1], 0.f);
            o.z = fmaxf(acc[r][2], 0.f);
            o.w = fmaxf(acc[r][3], 0.f);
            *(float4*)(out + (size_t)gr * D_FEAT + j0) = o;
        }
    }
}

// ---------------------------------------------------------------------------
// MLP layer 1: hidden[N,256] = relu(h @ W1 + b1); two 128-col passes.
// ---------------------------------------------------------------------------
__global__ __launch_bounds__(256) void mlp1_kernel(
        const float* __restrict__ h, const float* __restrict__ w1,
        const float* __restrict__ b1v, float* __restrict__ hidden) {
    __shared__ float hs[32][132];
    int tid  = threadIdx.x;
    int row0 = blockIdx.x * 32;
    for (int t = tid; t < 1024; t += 256) {
        int r = t >> 5;
        int c = (t & 31) * 4;
        int gr = row0 + r;
        float4 hv = make_float4(0.f, 0.f, 0.f, 0.f);
        if (gr < N_NODES) hv = *(const float4*)(h + (size_t)gr * D_FEAT + c);
        *(float4*)&hs[r][c] = hv;
    }
    __syncthreads();

    int tr = tid >> 5, tc = tid & 31;
    int ra = tr * 4;
#pragma unroll
    for (int half = 0; half < 2; half++) {
        int j0 = tc * 4 + half * 128;
        float acc[4][4];
        float b0 = b1v[j0], b1 = b1v[j0 + 1], b2 = b1v[j0 + 2], b3 = b1v[j0 + 3];
#pragma unroll
        for (int r = 0; r < 4; r++) { acc[r][0] = b0; acc[r][1] = b1; acc[r][2] = b2; acc[r][3] = b3; }
        for (int k = 0; k < D_FEAT; k += 4) {
            float4 a[4];
#pragma unroll
            for (int r = 0; r < 4; r++) a[r] = *(const float4*)&hs[ra + r][k];
#pragma unroll
            for (int kk = 0; kk < 4; kk++) {
                float4 b = *(const float4*)(w1 + (size_t)(k + kk) * HIDDEN + j0);
#pragma unroll
                for (int r = 0; r < 4; r++) {
                    float av = (&a[r].x)[kk];
                    acc[r][0] += av * b.x;
                    acc[r][1] += av * b.y;
                    acc[r][2] += av * b.z;
                    acc[r][3] += av * b.w;
                }
            }
        }
#pragma unroll
        for (int r = 0; r < 4; r++) {
            int gr = row0 + ra + r;
            if (gr < N_NODES) {
                float4 o;
                o.x = fmaxf(acc[r][0], 0.f);
                o.y = fmaxf(acc[r][1], 0.f);
                o.z = fmaxf(acc[r][2], 0.f);
                o.w = fmaxf(acc[r][3], 0.f);
                *(float4*)(hidden + (size_t)gr * HIDDEN + j0) = o;
            }
        }
    }
}

// ---------------------------------------------------------------------------
// MLP layer 2: out[N,40] = hidden @ W2 + b2. Block 320 = 8 row-groups x 40 cols.
// ---------------------------------------------------------------------------
__global__ __launch_bounds__(320) void mlp2_kernel(
        const float* __restrict__ hidden, const float* __restrict__ w2,
        const float* __restrict__ b2v, float* __restrict__ out) {
    __shared__ float hs[32][260];   // stride 260: rows land on different banks
    int tid  = threadIdx.x;
    int row0 = blockIdx.x * 32;
    for (int t = tid; t < 2048; t += 320) {
        int r = t >> 6;
        int c = (t & 63) * 4;
        int gr = row0 + r;
        float4 v = make_float4(0.f, 0.f, 0.f, 0.f);
        if (gr < N_NODES) v = *(const float4*)(hidden + (size_t)gr * HIDDEN + c);
        *(float4*)&hs[r][c] = v;
    }
    __syncthreads();

    int j  = tid % 40;
    int rg = tid / 40;              // 0..7
    float bb = b2v[j];
    float acc[4] = {bb, bb, bb, bb};
    for (int k = 0; k < HIDDEN; k += 4) {
        float4 a[4];
#pragma unroll
        for (int rr = 0; rr < 4; rr++) a[rr] = *(const float4*)&hs[rg + 8 * rr][k];
#pragma unroll
        for (int kk = 0; kk < 4; kk++) {
            float w = w2[(size_t)(k + kk) * LABELS + j];
#pragma unroll
            for (int rr = 0; rr < 4; rr++) acc[rr] += (&a[rr].x)[kk] * w;
        }
    }
#pragma unroll
    for (int rr = 0; rr < 4; rr++) {
        int gr = row0 + rg + 8 * rr;
        if (gr < N_NODES) out[(size_t)gr * LABELS + j] = acc[rr];
    }
}

// ---------------------------------------------------------------------------
extern "C" void kernel_launch(void* const* d_in, const int* in_sizes, int n_in,
                              void* d_out, int out_size, void* d_ws, size_t ws_size,
                              hipStream_t stream) {
    const float* x      = (const float*)d_in[0];
    const int*   ei     = (const int*)d_in[1];
    const float* selfk  = (const float*)d_in[2];
    const float* nbrk   = (const float*)d_in[3];
    const float* biases = (const float*)d_in[4];
    const float* w1     = (const float*)d_in[5];
    const float* b1     = (const float*)d_in[6];
    const float* w2     = (const float*)d_in[7];
    const float* b2     = (const float*)d_in[8];
    float* out = (float*)d_out;

    const int* row = ei;             // targets
    const int* col = ei + N_EDGES;   // sources

    char* ws = (char*)d_ws;
    size_t off = 0;
    auto alloc = [&](size_t bytes) -> char* {
        char* p = ws + off;
        off = (off + bytes + 255) & ~(size_t)255;
        return p;
    };
    int*   deg      = (int*)  alloc((size_t)N_NODES * 4);
    int*   rowstart = (int*)  alloc((size_t)N_NODES * 4);
    int*   cursor   = (int*)  alloc((size_t)N_NODES * 4);
    float* inv_deg  = (float*)alloc((size_t)N_NODES * 4);
    int*   csr_col  = (int*)  alloc((size_t)N_EDGES * 4);
    float* hA       = (float*)alloc((size_t)N_NODES * D_FEAT * 4);
    float* hB       = (float*)alloc((size_t)N_NODES * D_FEAT * 4);
    float* nbrbuf   = (float*)alloc((size_t)N_NODES * D_FEAT * 4);
    // hB (25.6MB) and nbrbuf (25.6MB) are contiguous (sizes are 256B multiples);
    // after layer 2 the live h is in hA, so hidden[N,256] (51.2MB) aliases hB+nbr.
    float* hidden   = hB;

    hipMemsetAsync(deg,    0, (size_t)N_NODES * 4, stream);
    hipMemsetAsync(cursor, 0, (size_t)N_NODES * 4, stream);

    deg_kernel <<<(N_EDGES + 255) / 256, 256, 0, stream>>>(row, deg);
    scan_kernel<<<1, 1024, 0, stream>>>(deg, rowstart, inv_deg);
    fill_kernel<<<(N_EDGES + 255) / 256, 256, 0, stream>>>(row, col, rowstart, cursor, csr_col);

    const int agg_blocks  = (N_NODES * 64 + 255) / 256;   // one wave per node
    const int tile_blocks = (N_NODES + 31) / 32;

    const float* hcur = x;
    float* bufs[3] = {hA, hB, hA};   // layer0: x->hA, layer1: hA->hB, layer2: hB->hA
    for (int L = 0; L < 3; L++) {
        agg_kernel<<<agg_blocks, 256, 0, stream>>>(hcur, csr_col, rowstart, deg,
                                                   inv_deg, nbrbuf);
        layer_kernel<<<tile_blocks, 256, 0, stream>>>(
            hcur, nbrbuf,
            selfk + (size_t)L * D_FEAT * HALF,
            nbrk  + (size_t)L * D_FEAT * HALF,
            biases + (size_t)L * (2 * HALF),
            bufs[L]);
        hcur = bufs[L];
    }

    mlp1_kernel<<<tile_blocks, 256, 0, stream>>>(hcur, w1, b1, hidden);
    mlp2_kernel<<<tile_blocks, 320, 0, stream>>>(hidden, w2, b2, out);
}

// Round 2
// 561.966 us; speedup vs baseline: 1.1287x; 1.1287x over previous
//
#include <hip/hip_runtime.h>
#include <hip/hip_bf16.h>
#include <cstdint>
#include <cstddef>

#define N_NODES 50000
#define N_EDGES 800000
#define D_FEAT  128
#define HALF    64
#define HIDDEN  256
#define LABELS  40

#define SCAN_BLOCKS 49   // 49 * 1024 = 50176 >= N_NODES

// ---------------------------------------------------------------------------
// CSR build: degree histogram -> 3-phase parallel scan -> bucket fill
// ---------------------------------------------------------------------------
__global__ void deg_kernel(const int* __restrict__ row, int* __restrict__ deg) {
    int e = blockIdx.x * blockDim.x + threadIdx.x;
    if (e < N_EDGES) atomicAdd(&deg[row[e]], 1);
}

// Phase 1: per-block exclusive scan (wave shuffle + LDS cross-wave), block totals.
__global__ __launch_bounds__(1024) void scan1_kernel(
        const int* __restrict__ deg, int* __restrict__ rowstart,
        float* __restrict__ inv_deg, int* __restrict__ blocksum) {
    __shared__ int wtot[16];
    int tid  = threadIdx.x;
    int i    = blockIdx.x * 1024 + tid;
    int lane = tid & 63;
    int wid  = tid >> 6;
    int v    = (i < N_NODES) ? deg[i] : 0;
    int s    = v;
#pragma unroll
    for (int off = 1; off < 64; off <<= 1) {
        int t = __shfl_up(s, off, 64);
        if (lane >= off) s += t;
    }
    if (lane == 63) wtot[wid] = s;          // inclusive wave total
    __syncthreads();
    if (wid == 0) {
        int wv = (lane < 16) ? wtot[lane] : 0;
        int ws = wv;
#pragma unroll
        for (int off = 1; off < 16; off <<= 1) {
            int t = __shfl_up(ws, off, 64);
            if (lane >= off) ws += t;
        }
        if (lane < 16) wtot[lane] = ws - wv;  // exclusive wave offsets
        if (lane == 15 && blocksum) blocksum[blockIdx.x] = ws;  // block total
    }
    __syncthreads();
    if (i < N_NODES) {
        rowstart[i] = wtot[wid] + s - v;     // block-local exclusive
        inv_deg[i]  = 1.0f / fmaxf((float)v, 1.0f);
    }
}

// Phase 2: one wave scans the 49 block totals (exclusive).
__global__ void scan2_kernel(int* __restrict__ blocksum) {
    int lane = threadIdx.x;
    int v = (lane < SCAN_BLOCKS) ? blocksum[lane] : 0;
    int s = v;
#pragma unroll
    for (int off = 1; off < 64; off <<= 1) {
        int t = __shfl_up(s, off, 64);
        if (lane >= off) s += t;
    }
    if (lane < SCAN_BLOCKS) blocksum[lane] = s - v;
}

// Phase 3: add block offsets; emit final rowstart AND cursor (= rowstart copy).
__global__ __launch_bounds__(1024) void scan3_kernel(
        int* __restrict__ rowstart, const int* __restrict__ blocksum,
        int* __restrict__ cursor) {
    int i = blockIdx.x * 1024 + threadIdx.x;
    if (i < N_NODES) {
        int r = rowstart[i] + blocksum[blockIdx.x];
        rowstart[i] = r;
        cursor[i]   = r;
    }
}

__global__ void fill_kernel(const int* __restrict__ row, const int* __restrict__ col,
                            int* __restrict__ cursor, int* __restrict__ csr_col) {
    int e = blockIdx.x * blockDim.x + threadIdx.x;
    if (e < N_EDGES) {
        int r = row[e];
        int pos = atomicAdd(&cursor[r], 1);   // cursor starts at rowstart[r]
        csr_col[pos] = col[e];
    }
}

// ---------------------------------------------------------------------------
// Mean-neighbor aggregation: one wave (64 lanes) per node, float2 per lane.
// Each edge read is one coalesced 512 B row. Writes nbr_mean (pre-scaled).
// ---------------------------------------------------------------------------
__global__ __launch_bounds__(256) void agg_kernel(
        const float* __restrict__ h, const int* __restrict__ csr_col,
        const int* __restrict__ rowstart, const int* __restrict__ deg,
        const float* __restrict__ inv_deg, float* __restrict__ nbr) {
    int gid  = blockIdx.x * blockDim.x + threadIdx.x;
    int node = gid >> 6;
    int lane = threadIdx.x & 63;
    if (node >= N_NODES) return;
    int start = rowstart[node];
    int d     = deg[node];
    float a0 = 0.f, a1 = 0.f;
    int j = 0;
    for (; j + 4 <= d; j += 4) {
        int s0 = csr_col[start + j + 0];
        int s1 = csr_col[start + j + 1];
        int s2 = csr_col[start + j + 2];
        int s3 = csr_col[start + j + 3];
        float2 v0 = *(const float2*)(h + (size_t)s0 * D_FEAT + lane * 2);
        float2 v1 = *(const float2*)(h + (size_t)s1 * D_FEAT + lane * 2);
        float2 v2 = *(const float2*)(h + (size_t)s2 * D_FEAT + lane * 2);
        float2 v3 = *(const float2*)(h + (size_t)s3 * D_FEAT + lane * 2);
        a0 += v0.x + v1.x + v2.x + v3.x;
        a1 += v0.y + v1.y + v2.y + v3.y;
    }
    for (; j < d; ++j) {
        int s = csr_col[start + j];
        float2 v = *(const float2*)(h + (size_t)s * D_FEAT + lane * 2);
        a0 += v.x; a1 += v.y;
    }
    float inv = inv_deg[node];
    float2 o; o.x = a0 * inv; o.y = a1 * inv;
    *(float2*)(nbr + (size_t)node * D_FEAT + lane * 2) = o;
}

// ---------------------------------------------------------------------------
// Layer GEMM: h_out[N,128] = relu([h@Wself | nbr@Wnbr] + bias)
// 32-row tiles in LDS (stride 132 to decouple banks), 4x4 register blocking.
// ---------------------------------------------------------------------------
__global__ __launch_bounds__(256) void layer_kernel(
        const float* __restrict__ h, const float* __restrict__ nbr,
        const float* __restrict__ wself, const float* __restrict__ wnbr,
        const float* __restrict__ bias, float* __restrict__ out) {
    __shared__ float hs[32][132];
    __shared__ float ns[32][132];
    int tid  = threadIdx.x;
    int row0 = blockIdx.x * 32;
    for (int t = tid; t < 1024; t += 256) {
        int r = t >> 5;
        int c = (t & 31) * 4;
        int gr = row0 + r;
        float4 hv = make_float4(0.f, 0.f, 0.f, 0.f);
        float4 nv = make_float4(0.f, 0.f, 0.f, 0.f);
        if (gr < N_NODES) {
            hv = *(const float4*)(h   + (size_t)gr * D_FEAT + c);
            nv = *(const float4*)(nbr + (size_t)gr * D_FEAT + c);
        }
        *(float4*)&hs[r][c] = hv;
        *(float4*)&ns[r][c] = nv;
    }
    __syncthreads();

    int tr = tid >> 5;        // 0..7 -> 4 rows each
    int tc = tid & 31;        // 0..31 -> 4 cols each
    int j0 = tc * 4;          // 0..124
    bool self_half = (j0 < HALF);
    const float (*A)[132] = self_half ? hs : ns;
    const float* W = self_half ? (wself + j0) : (wnbr + (j0 - HALF));
    int ra = tr * 4;

    float acc[4][4];
    float b0 = bias[j0], b1 = bias[j0 + 1], b2 = bias[j0 + 2], b3 = bias[j0 + 3];
#pragma unroll
    for (int r = 0; r < 4; r++) { acc[r][0] = b0; acc[r][1] = b1; acc[r][2] = b2; acc[r][3] = b3; }

    for (int k = 0; k < D_FEAT; k += 4) {
        float4 a[4];
#pragma unroll
        for (int r = 0; r < 4; r++) a[r] = *(const float4*)&A[ra + r][k];
#pragma unroll
        for (int kk = 0; kk < 4; kk++) {
            float4 b = *(const float4*)(W + (size_t)(k + kk) * HALF);
#pragma unroll
            for (int r = 0; r < 4; r++) {
                float av = (&a[r].x)[kk];
                acc[r][0] += av * b.x;
                acc[r][1] += av * b.y;
                acc[r][2] += av * b.z;
                acc[r][3] += av * b.w;
            }
        }
    }
#pragma unroll
    for (int r = 0; r < 4; r++) {
        int gr = row0 + ra + r;
        if (gr < N_NODES) {
            float4 o;
            o.x = fmaxf(acc[r][0], 0.f);
            o.y = fmaxf(acc[r][1], 0.f);
            o.z = fmaxf(acc[r][2], 0.f);
            o.w = fmaxf(acc[r][3], 0.f);
            *(float4*)(out + (size_t)gr * D_FEAT + j0) = o;
        }
    }
}

// ---------------------------------------------------------------------------
// MLP layer 1: hidden[N,256] = relu(h @ W1 + b1); two 128-col passes.
// ---------------------------------------------------------------------------
__global__ __launch_bounds__(256) void mlp1_kernel(
        const float* __restrict__ h, const float* __restrict__ w1,
        const float* __restrict__ b1v, float* __restrict__ hidden) {
    __shared__ float hs[32][132];
    int tid  = threadIdx.x;
    int row0 = blockIdx.x * 32;
    for (int t = tid; t < 1024; t += 256) {
        int r = t >> 5;
        int c = (t & 31) * 4;
        int gr = row0 + r;
        float4 hv = make_float4(0.f, 0.f, 0.f, 0.f);
        if (gr < N_NODES) hv = *(const float4*)(h + (size_t)gr * D_FEAT + c);
        *(float4*)&hs[r][c] = hv;
    }
    __syncthreads();

    int tr = tid >> 5, tc = tid & 31;
    int ra = tr * 4;
#pragma unroll
    for (int half = 0; half < 2; half++) {
        int j0 = tc * 4 + half * 128;
        float acc[4][4];
        float b0 = b1v[j0], b1 = b1v[j0 + 1], b2 = b1v[j0 + 2], b3 = b1v[j0 + 3];
#pragma unroll
        for (int r = 0; r < 4; r++) { acc[r][0] = b0; acc[r][1] = b1; acc[r][2] = b2; acc[r][3] = b3; }
        for (int k = 0; k < D_FEAT; k += 4) {
            float4 a[4];
#pragma unroll
            for (int r = 0; r < 4; r++) a[r] = *(const float4*)&hs[ra + r][k];
#pragma unroll
            for (int kk = 0; kk < 4; kk++) {
                float4 b = *(const float4*)(w1 + (size_t)(k + kk) * HIDDEN + j0);
#pragma unroll
                for (int r = 0; r < 4; r++) {
                    float av = (&a[r].x)[kk];
                    acc[r][0] += av * b.x;
                    acc[r][1] += av * b.y;
                    acc[r][2] += av * b.z;
                    acc[r][3] += av * b.w;
                }
            }
        }
#pragma unroll
        for (int r = 0; r < 4; r++) {
            int gr = row0 + ra + r;
            if (gr < N_NODES) {
                float4 o;
                o.x = fmaxf(acc[r][0], 0.f);
                o.y = fmaxf(acc[r][1], 0.f);
                o.z = fmaxf(acc[r][2], 0.f);
                o.w = fmaxf(acc[r][3], 0.f);
                *(float4*)(hidden + (size_t)gr * HIDDEN + j0) = o;
            }
        }
    }
}

// ---------------------------------------------------------------------------
// MLP layer 2: out[N,40] = hidden @ W2 + b2. Block 320 = 8 row-groups x 40 cols.
// ---------------------------------------------------------------------------
__global__ __launch_bounds__(320) void mlp2_kernel(
        const float* __restrict__ hidden, const float* __restrict__ w2,
        const float* __restrict__ b2v, float* __restrict__ out) {
    __shared__ float hs[32][260];   // stride 260: rows land on different banks
    int tid  = threadIdx.x;
    int row0 = blockIdx.x * 32;
    for (int t = tid; t < 2048; t += 320) {
        int r = t >> 6;
        int c = (t & 63) * 4;
        int gr = row0 + r;
        float4 v = make_float4(0.f, 0.f, 0.f, 0.f);
        if (gr < N_NODES) v = *(const float4*)(hidden + (size_t)gr * HIDDEN + c);
        *(float4*)&hs[r][c] = v;
    }
    __syncthreads();

    int j  = tid % 40;
    int rg = tid / 40;              // 0..7
    float bb = b2v[j];
    float acc[4] = {bb, bb, bb, bb};
    for (int k = 0; k < HIDDEN; k += 4) {
        float4 a[4];
#pragma unroll
        for (int rr = 0; rr < 4; rr++) a[rr] = *(const float4*)&hs[rg + 8 * rr][k];
#pragma unroll
        for (int kk = 0; kk < 4; kk++) {
            float w = w2[(size_t)(k + kk) * LABELS + j];
#pragma unroll
            for (int rr = 0; rr < 4; rr++) acc[rr] += (&a[rr].x)[kk] * w;
        }
    }
#pragma unroll
    for (int rr = 0; rr < 4; rr++) {
        int gr = row0 + rg + 8 * rr;
        if (gr < N_NODES) out[(size_t)gr * LABELS + j] = acc[rr];
    }
}

// ---------------------------------------------------------------------------
extern "C" void kernel_launch(void* const* d_in, const int* in_sizes, int n_in,
                              void* d_out, int out_size, void* d_ws, size_t ws_size,
                              hipStream_t stream) {
    const float* x      = (const float*)d_in[0];
    const int*   ei     = (const int*)d_in[1];
    const float* selfk  = (const float*)d_in[2];
    const float* nbrk   = (const float*)d_in[3];
    const float* biases = (const float*)d_in[4];
    const float* w1     = (const float*)d_in[5];
    const float* b1     = (const float*)d_in[6];
    const float* w2     = (const float*)d_in[7];
    const float* b2     = (const float*)d_in[8];
    float* out = (float*)d_out;

    const int* row = ei;             // targets
    const int* col = ei + N_EDGES;   // sources

    char* ws = (char*)d_ws;
    size_t off = 0;
    auto alloc = [&](size_t bytes) -> char* {
        char* p = ws + off;
        off = (off + bytes + 255) & ~(size_t)255;
        return p;
    };
    int*   deg      = (int*)  alloc((size_t)N_NODES * 4);
    int*   rowstart = (int*)  alloc((size_t)N_NODES * 4);
    int*   cursor   = (int*)  alloc((size_t)N_NODES * 4);
    float* inv_deg  = (float*)alloc((size_t)N_NODES * 4);
    int*   blocksum = (int*)  alloc((size_t)SCAN_BLOCKS * 4);
    int*   csr_col  = (int*)  alloc((size_t)N_EDGES * 4);
    float* hA       = (float*)alloc((size_t)N_NODES * D_FEAT * 4);
    float* hB       = (float*)alloc((size_t)N_NODES * D_FEAT * 4);
    float* nbrbuf   = (float*)alloc((size_t)N_NODES * D_FEAT * 4);
    // hB (25.6MB) and nbrbuf (25.6MB) are contiguous (sizes are 256B multiples);
    // after layer 2 the live h is in hA, so hidden[N,256] (51.2MB) aliases hB+nbr.
    float* hidden   = hB;

    hipMemsetAsync(deg, 0, (size_t)N_NODES * 4, stream);

    deg_kernel <<<(N_EDGES + 255) / 256, 256, 0, stream>>>(row, deg);
    scan1_kernel<<<SCAN_BLOCKS, 1024, 0, stream>>>(deg, rowstart, inv_deg, blocksum);
    scan2_kernel<<<1, 64, 0, stream>>>(blocksum);
    scan3_kernel<<<SCAN_BLOCKS, 1024, 0, stream>>>(rowstart, blocksum, cursor);
    fill_kernel<<<(N_EDGES + 255) / 256, 256, 0, stream>>>(row, col, cursor, csr_col);

    const int agg_blocks  = (N_NODES * 64 + 255) / 256;   // one wave per node
    const int tile_blocks = (N_NODES + 31) / 32;

    const float* hcur = x;
    float* bufs[3] = {hA, hB, hA};   // layer0: x->hA, layer1: hA->hB, layer2: hB->hA
    for (int L = 0; L < 3; L++) {
        agg_kernel<<<agg_blocks, 256, 0, stream>>>(hcur, csr_col, rowstart, deg,
                                                   inv_deg, nbrbuf);
        layer_kernel<<<tile_blocks, 256, 0, stream>>>(
            hcur, nbrbuf,
            selfk + (size_t)L * D_FEAT * HALF,
            nbrk  + (size_t)L * D_FEAT * HALF,
            biases + (size_t)L * (2 * HALF),
            bufs[L]);
        hcur = bufs[L];
    }

    mlp1_kernel<<<tile_blocks, 256, 0, stream>>>(hcur, w1, b1, hidden);
    mlp2_kernel<<<tile_blocks, 320, 0, stream>>>(hidden, w2, b2, out);
}

// Round 3
// 375.873 us; speedup vs baseline: 1.6875x; 1.4951x over previous
//
#include <hip/hip_runtime.h>
#include <hip/hip_bf16.h>
#include <cstdint>
#include <cstddef>

#define N_NODES 50000
#define N_EDGES 800000
#define D_FEAT  128
#define HALF    64
#define HIDDEN  256
#define LABELS  40

#define SCAN_BLOCKS 49   // 49 * 1024 = 50176 >= N_NODES

typedef __attribute__((ext_vector_type(8))) short bf16x8;
typedef __attribute__((ext_vector_type(4))) float f32x4;

// Packed-weight layout offsets (in bf16 elements).
// layer self L: L*8192 ; layer nbr L: 24576 + L*8192 ; w1: 49152 ; w2: 81920 (N padded 40->48)
#define PK_SELF(L) ((size_t)(L) * 8192)
#define PK_NBR(L)  (24576 + (size_t)(L) * 8192)
#define PK_W1      49152
#define PK_W2      81920
#define PK_TOTAL   94208

__device__ inline uint16_t f2bf_bits(float f) {
    __hip_bfloat16 b = __float2bfloat16(f);
    uint16_t u; __builtin_memcpy(&u, &b, 2); return u;
}

// ---------------------------------------------------------------------------
// CSR build: degree histogram -> 3-phase parallel scan -> bucket fill
// ---------------------------------------------------------------------------
__global__ void deg_kernel(const int* __restrict__ row, int* __restrict__ deg) {
    int e = blockIdx.x * blockDim.x + threadIdx.x;
    if (e < N_EDGES) atomicAdd(&deg[row[e]], 1);
}

__global__ __launch_bounds__(1024) void scan1_kernel(
        const int* __restrict__ deg, int* __restrict__ rowstart,
        float* __restrict__ inv_deg, int* __restrict__ blocksum) {
    __shared__ int wtot[16];
    int tid  = threadIdx.x;
    int i    = blockIdx.x * 1024 + tid;
    int lane = tid & 63;
    int wid  = tid >> 6;
    int v    = (i < N_NODES) ? deg[i] : 0;
    int s    = v;
#pragma unroll
    for (int off = 1; off < 64; off <<= 1) {
        int t = __shfl_up(s, off, 64);
        if (lane >= off) s += t;
    }
    if (lane == 63) wtot[wid] = s;
    __syncthreads();
    if (wid == 0) {
        int wv = (lane < 16) ? wtot[lane] : 0;
        int ws = wv;
#pragma unroll
        for (int off = 1; off < 16; off <<= 1) {
            int t = __shfl_up(ws, off, 64);
            if (lane >= off) ws += t;
        }
        if (lane < 16) wtot[lane] = ws - wv;
        if (lane == 15 && blocksum) blocksum[blockIdx.x] = ws;
    }
    __syncthreads();
    if (i < N_NODES) {
        rowstart[i] = wtot[wid] + s - v;
        inv_deg[i]  = 1.0f / fmaxf((float)v, 1.0f);
    }
}

__global__ void scan2_kernel(int* __restrict__ blocksum) {
    int lane = threadIdx.x;
    int v = (lane < SCAN_BLOCKS) ? blocksum[lane] : 0;
    int s = v;
#pragma unroll
    for (int off = 1; off < 64; off <<= 1) {
        int t = __shfl_up(s, off, 64);
        if (lane >= off) s += t;
    }
    if (lane < SCAN_BLOCKS) blocksum[lane] = s - v;
}

__global__ __launch_bounds__(1024) void scan3_kernel(
        int* __restrict__ rowstart, const int* __restrict__ blocksum,
        int* __restrict__ cursor) {
    int i = blockIdx.x * 1024 + threadIdx.x;
    if (i < N_NODES) {
        int r = rowstart[i] + blocksum[blockIdx.x];
        rowstart[i] = r;
        cursor[i]   = r;
    }
}

__global__ void fill_kernel(const int* __restrict__ row, const int* __restrict__ col,
                            int* __restrict__ cursor, int* __restrict__ csr_col) {
    int e = blockIdx.x * blockDim.x + threadIdx.x;
    if (e < N_EDGES) {
        int r = row[e];
        int pos = atomicAdd(&cursor[r], 1);
        csr_col[pos] = col[e];
    }
}

// ---------------------------------------------------------------------------
// x (fp32) -> bf16
// ---------------------------------------------------------------------------
__global__ __launch_bounds__(256) void xcast_kernel(
        const float* __restrict__ x, __hip_bfloat16* __restrict__ xb) {
    size_t i = (size_t)(blockIdx.x * blockDim.x + threadIdx.x) * 4;
    if (i >= (size_t)N_NODES * D_FEAT) return;
    float4 v = *(const float4*)(x + i);
    uint2 p;
    p.x = (uint32_t)f2bf_bits(v.x) | ((uint32_t)f2bf_bits(v.y) << 16);
    p.y = (uint32_t)f2bf_bits(v.z) | ((uint32_t)f2bf_bits(v.w) << 16);
    *(uint2*)((uint16_t*)xb + i) = p;
}

// ---------------------------------------------------------------------------
// Pack all weights to bf16 in MFMA B-fragment order.
// B-frag read in GEMM: lane l, k-step ks, n-subtile ns ->
//   pack[((ns*ksteps + ks)*64 + l)*8 + j] = W[ks*32 + (l>>4)*8 + j][ns*16 + (l&15)]
// blockIdx.y selects matrix: 0-2 selfk L, 3-5 nbrk L, 6 w1, 7 w2(pad 40->48)
// ---------------------------------------------------------------------------
__global__ __launch_bounds__(256) void pack_all_kernel(
        const float* __restrict__ selfk, const float* __restrict__ nbrk,
        const float* __restrict__ w1, const float* __restrict__ w2,
        __hip_bfloat16* __restrict__ wpack) {
    int m = blockIdx.y;
    const float* W; int K, Ncols, Npad; size_t dstoff;
    if (m < 3)      { W = selfk + (size_t)m*D_FEAT*HALF;      K=128; Ncols=64;  Npad=64;  dstoff = PK_SELF(m); }
    else if (m < 6) { W = nbrk  + (size_t)(m-3)*D_FEAT*HALF;  K=128; Ncols=64;  Npad=64;  dstoff = PK_NBR(m-3); }
    else if (m == 6){ W = w1;                                 K=128; Ncols=256; Npad=256; dstoff = PK_W1; }
    else            { W = w2;                                 K=256; Ncols=40;  Npad=48;  dstoff = PK_W2; }
    int ksteps = K / 32;
    int total  = ksteps * (Npad / 16) * 64;
    int t = blockIdx.x * blockDim.x + threadIdx.x;
    if (t >= total) return;
    int lane = t & 63;
    int rest = t >> 6;
    int ks   = rest % ksteps;
    int ns   = rest / ksteps;
    int colb = ns * 16 + (lane & 15);
    int kb   = ks * 32 + (lane >> 4) * 8;
    __hip_bfloat16* dst = wpack + dstoff + (size_t)t * 8;
#pragma unroll
    for (int j = 0; j < 8; j++) {
        float v = (colb < Ncols) ? W[(size_t)(kb + j) * Ncols + colb] : 0.f;
        dst[j] = __float2bfloat16(v);
    }
}

// ---------------------------------------------------------------------------
// Mean-neighbor aggregation (bf16): one wave per node, 4B (2 bf16) per lane.
// ---------------------------------------------------------------------------
__global__ __launch_bounds__(256) void agg_kernel(
        const __hip_bfloat16* __restrict__ h, const int* __restrict__ csr_col,
        const int* __restrict__ rowstart, const int* __restrict__ deg,
        const float* __restrict__ inv_deg, __hip_bfloat16* __restrict__ nbr) {
    int gid  = blockIdx.x * blockDim.x + threadIdx.x;
    int node = gid >> 6;
    int lane = threadIdx.x & 63;
    if (node >= N_NODES) return;
    int start = rowstart[node];
    int d     = deg[node];
    const uint32_t* hw = (const uint32_t*)h;   // row = 64 dwords
    float a0 = 0.f, a1 = 0.f;
    int j = 0;
    for (; j + 4 <= d; j += 4) {
        int s0 = csr_col[start + j + 0];
        int s1 = csr_col[start + j + 1];
        int s2 = csr_col[start + j + 2];
        int s3 = csr_col[start + j + 3];
        uint32_t u0 = hw[(size_t)s0 * 64 + lane];
        uint32_t u1 = hw[(size_t)s1 * 64 + lane];
        uint32_t u2 = hw[(size_t)s2 * 64 + lane];
        uint32_t u3 = hw[(size_t)s3 * 64 + lane];
        a0 += __uint_as_float(u0 << 16) + __uint_as_float(u1 << 16)
            + __uint_as_float(u2 << 16) + __uint_as_float(u3 << 16);
        a1 += __uint_as_float(u0 & 0xffff0000u) + __uint_as_float(u1 & 0xffff0000u)
            + __uint_as_float(u2 & 0xffff0000u) + __uint_as_float(u3 & 0xffff0000u);
    }
    for (; j < d; ++j) {
        int s = csr_col[start + j];
        uint32_t u = hw[(size_t)s * 64 + lane];
        a0 += __uint_as_float(u << 16);
        a1 += __uint_as_float(u & 0xffff0000u);
    }
    float inv = inv_deg[node];
    uint32_t pv = (uint32_t)f2bf_bits(a0 * inv) | ((uint32_t)f2bf_bits(a1 * inv) << 16);
    ((uint32_t*)nbr)[(size_t)node * 64 + lane] = pv;
}

// ---------------------------------------------------------------------------
// Layer GEMM (MFMA): out[N,128] = relu([h@Wself | nbr@Wnbr] + bias), bf16 out.
// Block = 4 waves; waves 0,1 -> self half rows r0/r0+16; waves 2,3 -> nbr half.
// A-frag: lane l holds A[m=l&15][k=ks*32+(l>>4)*8+j] (16B load from global).
// C/D: col=l&15, row=(l>>4)*4+reg (verified m89).
// ---------------------------------------------------------------------------
__global__ __launch_bounds__(256) void layer_mfma_kernel(
        const __hip_bfloat16* __restrict__ h, const __hip_bfloat16* __restrict__ nbr,
        const __hip_bfloat16* __restrict__ wpack_self,
        const __hip_bfloat16* __restrict__ wpack_nbr,
        const float* __restrict__ bias, __hip_bfloat16* __restrict__ out) {
    int wave = threadIdx.x >> 6, lane = threadIdx.x & 63;
    int half = wave >> 1;                       // 0: self(h), 1: nbr
    int row0 = blockIdx.x * 32 + (wave & 1) * 16;
    if (row0 >= N_NODES) return;                // 16 | 50000 -> wave-uniform guard
    int lrow = lane & 15, lgrp = lane >> 4;
    const __hip_bfloat16* A  = half ? nbr : h;
    const __hip_bfloat16* wp = half ? wpack_nbr : wpack_self;
    const __hip_bfloat16* arow = A + (size_t)(row0 + lrow) * D_FEAT + lgrp * 8;

    f32x4 acc[4] = {};
    for (int ks = 0; ks < 4; ks++) {
        bf16x8 af = *(const bf16x8*)(arow + ks * 32);
#pragma unroll
        for (int ns = 0; ns < 4; ns++) {
            bf16x8 bfr = *(const bf16x8*)(wp + ((size_t)(ns * 4 + ks) * 64 + lane) * 8);
            acc[ns] = __builtin_amdgcn_mfma_f32_16x16x32_bf16(af, bfr, acc[ns], 0, 0, 0);
        }
    }
    int colbase = half * 64;
#pragma unroll
    for (int ns = 0; ns < 4; ns++) {
        int col = colbase + ns * 16 + lrow;
        float bv = bias[col];
#pragma unroll
        for (int i = 0; i < 4; i++) {
            int r = row0 + lgrp * 4 + i;
            float v = fmaxf(acc[ns][i] + bv, 0.f);
            out[(size_t)r * D_FEAT + col] = __float2bfloat16(v);
        }
    }
}

// ---------------------------------------------------------------------------
// MLP1 (MFMA): hidden[N,256] = relu(h @ W1 + b1), bf16 out. Wave = 16 rows.
// ---------------------------------------------------------------------------
__global__ __launch_bounds__(256) void mlp1_mfma_kernel(
        const __hip_bfloat16* __restrict__ h, const __hip_bfloat16* __restrict__ w1p,
        const float* __restrict__ b1, __hip_bfloat16* __restrict__ hidden) {
    int wave = threadIdx.x >> 6, lane = threadIdx.x & 63;
    int row0 = blockIdx.x * 64 + wave * 16;
    if (row0 >= N_NODES) return;
    int lrow = lane & 15, lgrp = lane >> 4;
    const __hip_bfloat16* arow = h + (size_t)(row0 + lrow) * D_FEAT + lgrp * 8;

    f32x4 acc[16] = {};
    for (int ks = 0; ks < 4; ks++) {
        bf16x8 af = *(const bf16x8*)(arow + ks * 32);
#pragma unroll
        for (int ns = 0; ns < 16; ns++) {
            bf16x8 bfr = *(const bf16x8*)(w1p + ((size_t)(ns * 4 + ks) * 64 + lane) * 8);
            acc[ns] = __builtin_amdgcn_mfma_f32_16x16x32_bf16(af, bfr, acc[ns], 0, 0, 0);
        }
    }
#pragma unroll
    for (int ns = 0; ns < 16; ns++) {
        int col = ns * 16 + lrow;
        float bv = b1[col];
#pragma unroll
        for (int i = 0; i < 4; i++) {
            int r = row0 + lgrp * 4 + i;
            float v = fmaxf(acc[ns][i] + bv, 0.f);
            hidden[(size_t)r * HIDDEN + col] = __float2bfloat16(v);
        }
    }
}

// ---------------------------------------------------------------------------
// MLP2 (MFMA): out[N,40] = hidden @ W2 + b2 (fp32 out, N padded 40->48).
// ---------------------------------------------------------------------------
__global__ __launch_bounds__(256) void mlp2_mfma_kernel(
        const __hip_bfloat16* __restrict__ hidden, const __hip_bfloat16* __restrict__ w2p,
        const float* __restrict__ b2, float* __restrict__ out) {
    int wave = threadIdx.x >> 6, lane = threadIdx.x & 63;
    int row0 = blockIdx.x * 64 + wave * 16;
    if (row0 >= N_NODES) return;
    int lrow = lane & 15, lgrp = lane >> 4;
    const __hip_bfloat16* arow = hidden + (size_t)(row0 + lrow) * HIDDEN + lgrp * 8;

    f32x4 acc[3] = {};
    for (int ks = 0; ks < 8; ks++) {
        bf16x8 af = *(const bf16x8*)(arow + ks * 32);
#pragma unroll
        for (int ns = 0; ns < 3; ns++) {
            bf16x8 bfr = *(const bf16x8*)(w2p + ((size_t)(ns * 8 + ks) * 64 + lane) * 8);
            acc[ns] = __builtin_amdgcn_mfma_f32_16x16x32_bf16(af, bfr, acc[ns], 0, 0, 0);
        }
    }
#pragma unroll
    for (int ns = 0; ns < 3; ns++) {
        int col = ns * 16 + lrow;
        if (col < LABELS) {
            float bv = b2[col];
#pragma unroll
            for (int i = 0; i < 4; i++) {
                int r = row0 + lgrp * 4 + i;
                out[(size_t)r * LABELS + col] = acc[ns][i] + bv;
            }
        }
    }
}

// ---------------------------------------------------------------------------
extern "C" void kernel_launch(void* const* d_in, const int* in_sizes, int n_in,
                              void* d_out, int out_size, void* d_ws, size_t ws_size,
                              hipStream_t stream) {
    const float* x      = (const float*)d_in[0];
    const int*   ei     = (const int*)d_in[1];
    const float* selfk  = (const float*)d_in[2];
    const float* nbrk   = (const float*)d_in[3];
    const float* biases = (const float*)d_in[4];
    const float* w1     = (const float*)d_in[5];
    const float* b1     = (const float*)d_in[6];
    const float* w2     = (const float*)d_in[7];
    const float* b2     = (const float*)d_in[8];
    float* out = (float*)d_out;

    const int* row = ei;             // targets
    const int* col = ei + N_EDGES;   // sources

    char* ws = (char*)d_ws;
    size_t off = 0;
    auto alloc = [&](size_t bytes) -> char* {
        char* p = ws + off;
        off = (off + bytes + 255) & ~(size_t)255;
        return p;
    };
    int*   deg      = (int*)  alloc((size_t)N_NODES * 4);
    int*   rowstart = (int*)  alloc((size_t)N_NODES * 4);
    int*   cursor   = (int*)  alloc((size_t)N_NODES * 4);
    float* inv_deg  = (float*)alloc((size_t)N_NODES * 4);
    int*   blocksum = (int*)  alloc((size_t)SCAN_BLOCKS * 4);
    int*   csr_col  = (int*)  alloc((size_t)N_EDGES * 4);
    __hip_bfloat16* wpack  = (__hip_bfloat16*)alloc(PK_TOTAL * 2);
    __hip_bfloat16* xb     = (__hip_bfloat16*)alloc((size_t)N_NODES * D_FEAT * 2);
    __hip_bfloat16* hA     = (__hip_bfloat16*)alloc((size_t)N_NODES * D_FEAT * 2);
    __hip_bfloat16* hB     = (__hip_bfloat16*)alloc((size_t)N_NODES * D_FEAT * 2);
    __hip_bfloat16* nbrbuf = (__hip_bfloat16*)alloc((size_t)N_NODES * D_FEAT * 2);
    __hip_bfloat16* hidden = (__hip_bfloat16*)alloc((size_t)N_NODES * HIDDEN * 2);

    hipMemsetAsync(deg, 0, (size_t)N_NODES * 4, stream);

    deg_kernel <<<(N_EDGES + 255) / 256, 256, 0, stream>>>(row, deg);
    scan1_kernel<<<SCAN_BLOCKS, 1024, 0, stream>>>(deg, rowstart, inv_deg, blocksum);
    scan2_kernel<<<1, 64, 0, stream>>>(blocksum);
    scan3_kernel<<<SCAN_BLOCKS, 1024, 0, stream>>>(rowstart, blocksum, cursor);
    fill_kernel<<<(N_EDGES + 255) / 256, 256, 0, stream>>>(row, col, cursor, csr_col);

    xcast_kernel<<<(N_NODES * D_FEAT / 4 + 255) / 256, 256, 0, stream>>>(x, xb);
    dim3 pgrid(16, 8);
    pack_all_kernel<<<pgrid, 256, 0, stream>>>(selfk, nbrk, w1, w2, wpack);

    const int agg_blocks   = (N_NODES * 64 + 255) / 256;   // one wave per node
    const int layer_blocks = (N_NODES + 31) / 32;
    const int mlp_blocks   = (N_NODES + 63) / 64;

    const __hip_bfloat16* hcur = xb;
    __hip_bfloat16* bufs[3] = {hA, hB, hA};
    for (int L = 0; L < 3; L++) {
        agg_kernel<<<agg_blocks, 256, 0, stream>>>(hcur, csr_col, rowstart, deg,
                                                   inv_deg, nbrbuf);
        layer_mfma_kernel<<<layer_blocks, 256, 0, stream>>>(
            hcur, nbrbuf, wpack + PK_SELF(L), wpack + PK_NBR(L),
            biases + (size_t)L * (2 * HALF), bufs[L]);
        hcur = bufs[L];
    }

    mlp1_mfma_kernel<<<mlp_blocks, 256, 0, stream>>>(hcur, wpack + PK_W1, b1, hidden);
    mlp2_mfma_kernel<<<mlp_blocks, 256, 0, stream>>>(hidden, wpack + PK_W2, b2, out);
}